// Round 6
// baseline (205.035 us; speedup 1.0000x reference)
//
#include <hip/hip_runtime.h>
#include <hip/hip_bf16.h>
#include <cmath>

// GRU cell fused, round 6: register-software-pipelined fused GEMM.
// BM=256 x BN=64, 8 waves (4m x 2n), BK=32. Per K-step, 3 phases; every
// ds_read group issued ONE phase before its MFMA consumer, counted lgkmcnt
// gates (8/8/12, never 0 between phases), ONE barrier per step, vmcnt(0)
// only on loads issued a full step earlier. A-buf x2 + W-buf x3 in LDS
// (136KB), A-fragments double-buffered in registers, 6-step unrolled loop.
// ws layout (ushort elems):
//   wsIn @ 0        : [64 mtile][32 kstep][128x32 swz]   8,388,608
//   wsHx @ 8388608  : same                                8,388,608
//   wsW  @ 16777216 : [16 j][32 kstep][6 tile][64x32 swz] 6,291,456
//     tile order: 0=Wih_z 1=Whh_z 2=Wih_r 3=Whh_r 4=Wc 5=Whc

typedef __attribute__((ext_vector_type(8))) short bf16x8;
typedef __attribute__((ext_vector_type(4))) float f32x4;
typedef unsigned int u32;

typedef const __attribute__((address_space(1))) u32 gu32;
typedef __attribute__((address_space(3))) u32 su32;

__device__ __forceinline__ unsigned short f2bf(float f) {
  union { float f; u32 u; } v; v.f = f;
  u32 u = v.u;
  u += 0x7FFFu + ((u >> 16) & 1u);   // RTNE
  return (unsigned short)(u >> 16);
}
__device__ __forceinline__ void gload16(void* ldsp, const void* gp) {
  __builtin_amdgcn_global_load_lds((gu32*)gp, (su32*)ldsp, 16, 0, 0);
}
__device__ __forceinline__ float sigmf(float x) { return 1.0f / (1.0f + __expf(-x)); }

#define SB0   __builtin_amdgcn_sched_barrier(0)
#define LGKM(N) do { asm volatile("s_waitcnt lgkmcnt(" #N ")" ::: "memory"); SB0; } while (0)
#define VM0     do { asm volatile("s_waitcnt vmcnt(0)"        ::: "memory"); SB0; } while (0)
#define VM7     do { asm volatile("s_waitcnt vmcnt(7)"        ::: "memory"); SB0; } while (0)
#define BARR    do { SB0; __builtin_amdgcn_s_barrier(); SB0; } while (0)

// ---------------- prepass: fp32 -> bf16 swizzled tiles ----------------
__global__ __launch_bounds__(256) void cvt_all(
    const float* __restrict__ In, const float* __restrict__ Hx,
    const float* __restrict__ Wih, const float* __restrict__ Whh,
    const float* __restrict__ Wc,  const float* __restrict__ Whc,
    unsigned short* __restrict__ ws)
{
  unsigned short* wsIn = ws;
  unsigned short* wsHx = ws + 8388608;
  unsigned short* wsW  = ws + 16777216;
  int bid = blockIdx.x;
  if (bid < 8192) {
    int gid = bid * 256 + threadIdx.x;
    const float* src; unsigned short* dst; int idx;
    if (gid < (1 << 20)) { src = In; dst = wsIn; idx = gid; }
    else                 { src = Hx; dst = wsHx; idx = gid - (1 << 20); }
    int m = idx >> 7, t = idx & 127;
    const float4* s = (const float4*)(src + (size_t)m * 1024 + t * 8);
    float4 a = s[0], b = s[1];
    int row = m & 127;
    size_t tile = (size_t)(m >> 7) * 32 + (t >> 2);
    int sw = (t & 3) ^ ((row >> 1) & 3);
    bf16x8 v;
    v[0] = (short)f2bf(a.x); v[1] = (short)f2bf(a.y); v[2] = (short)f2bf(a.z); v[3] = (short)f2bf(a.w);
    v[4] = (short)f2bf(b.x); v[5] = (short)f2bf(b.y); v[6] = (short)f2bf(b.z); v[7] = (short)f2bf(b.w);
    *(bf16x8*)(dst + tile * 4096 + row * 32 + sw * 8) = v;
  } else {
    int wb = bid - 8192;                   // 0..3071
    const float* W; int NW, tz, local;
    if (wb < 1024)      { W = Wih; NW = 2048; tz = 0; local = wb; }
    else if (wb < 2048) { W = Whh; NW = 2048; tz = 1; local = wb - 1024; }
    else if (wb < 2560) { W = Wc;  NW = 1024; tz = 4; local = wb - 2048; }
    else                { W = Whc; NW = 1024; tz = 5; local = wb - 2560; }
    int nb = local >> 5, kb = local & 31;
    int jj   = nb & 15;
    int tile = (tz < 4) ? (nb < 16 ? tz : tz + 2) : tz;   // Wih/Whh: z cols->0/1, r cols->2/3
    int n  = nb * 64 + (threadIdx.x & 63);
    int k0 = kb * 32 + (threadIdx.x >> 6) * 8;
    bf16x8 v;
    #pragma unroll
    for (int b = 0; b < 8; ++b) v[b] = (short)f2bf(W[(size_t)(k0 + b) * NW + n]);
    int row = n & 63;
    int sw  = ((k0 >> 3) & 3) ^ ((row >> 1) & 3);
    *(bf16x8*)(wsW + (size_t)jj * 393216 + (size_t)kb * 12288 + tile * 2048 + row * 32 + sw * 8) = v;
  }
}

// ---------------- fused GEMM + GRU epilogue ----------------
// LDS elems (ushort): Abuf0 @0 (16384), Abuf1 @16384, Wbuf0 @32768 (12288),
//   Wbuf1 @45056, Wbuf2 @57344. total 69632 elems = 136KB.
__global__ __launch_bounds__(512, 2) void gru_gemm(
    const unsigned short* __restrict__ ws,
    const float* __restrict__ Hx,
    const float* __restrict__ bih, const float* __restrict__ bhh,
    const float* __restrict__ bc, const float* __restrict__ bhc,
    float* __restrict__ out)
{
  __shared__ unsigned short lds[69632];
  const int tid = threadIdx.x, lane = tid & 63, wave = tid >> 6;
  const int wm = wave >> 1, wn = wave & 1;      // 4m x 2n
  const int bid = blockIdx.x;
  const int swz = (bid & 7) * 64 + (bid >> 3);  // bijective XCD swizzle (512%8==0)
  const int j = swz & 15, i = swz >> 4;
  const int r15 = lane & 15, q = lane >> 4;
  const int slot = q ^ ((r15 >> 1) & 3);

  // LDS read bases (elem offsets)
  const int vA  = (wm >> 1) * 4096 + (wm & 1) * 2048 + r15 * 32 + slot * 8;
  const int vW0 = 32768 + wn * 1024 + r15 * 32 + slot * 8;
  const int vW1 = vW0 + 12288;
  const int vW2 = vW0 + 24576;

  // stage source offsets (elems from ws base); each wave: 4 A-chunks, 3 W-chunks
  const int ac = wave * 4;
  u32 oA = (ac < 16 ? (u32)(2 * i + (ac >> 3)) * 131072u
                    : 8388608u + (u32)(2 * i + ((ac >> 3) - 2)) * 131072u)
           + (u32)(ac & 7) * 512u + (u32)lane * 8u;
  u32 oW = 16777216u + (u32)j * 393216u + (u32)(wave * 3) * 512u + (u32)lane * 8u;

  f32x4 accZ[4][2], accR[4][2], accC[4][2], accH[4][2];
  #pragma unroll
  for (int a = 0; a < 4; ++a)
    #pragma unroll
    for (int b = 0; b < 2; ++b) {
      accZ[a][b] = (f32x4)(0.0f); accR[a][b] = (f32x4)(0.0f);
      accC[a][b] = (f32x4)(0.0f); accH[a][b] = (f32x4)(0.0f);
    }

  bf16x8 aIn0[4], aHx0[4], aIn1[4], aHx1[4];
  bf16x8 wzA[2], wzB[2], wrA[2], wrB[2], wcA[2], whB[2];

  #define LA(ACb, SEL, MR) (*(const bf16x8*)&lds[(ACb)*16384 + (SEL)*8192 + (MR)*512 + vA])
  #define LW(K, T, NR)     (*(const bf16x8*)&lds[vW##K + (T)*2048 + (NR)*512])

  #define STAGE(ACb, WSv) { \
    _Pragma("unroll") for (int c_ = 0; c_ < 4; ++c_) \
      gload16((void*)&lds[(ACb)*16384 + (wave*4 + c_)*512], (const void*)(ws + oA + c_*512u)); \
    _Pragma("unroll") for (int c_ = 0; c_ < 3; ++c_) \
      gload16((void*)&lds[32768 + (WSv)*12288 + (wave*3 + c_)*512], (const void*)(ws + oW + c_*512u)); \
  }

  #define MFMA_(a,b,c) __builtin_amdgcn_mfma_f32_16x16x32_bf16(a, b, c, 0, 0, 0)
  #define MZ(AI, AH) { __builtin_amdgcn_s_setprio(1); \
    _Pragma("unroll") for (int m_=0;m_<4;++m_) { _Pragma("unroll") for (int n_=0;n_<2;++n_) { \
      accZ[m_][n_] = MFMA_(AI[m_], wzA[n_], accZ[m_][n_]); \
      accZ[m_][n_] = MFMA_(AH[m_], wzB[n_], accZ[m_][n_]); } } \
    __builtin_amdgcn_s_setprio(0); }
  #define MR_(AI, AH) { __builtin_amdgcn_s_setprio(1); \
    _Pragma("unroll") for (int m_=0;m_<4;++m_) { _Pragma("unroll") for (int n_=0;n_<2;++n_) { \
      accR[m_][n_] = MFMA_(AI[m_], wrA[n_], accR[m_][n_]); \
      accR[m_][n_] = MFMA_(AH[m_], wrB[n_], accR[m_][n_]); } } \
    __builtin_amdgcn_s_setprio(0); }
  #define MCH(AI, AH) { __builtin_amdgcn_s_setprio(1); \
    _Pragma("unroll") for (int m_=0;m_<4;++m_) { _Pragma("unroll") for (int n_=0;n_<2;++n_) { \
      accC[m_][n_] = MFMA_(AI[m_], wcA[n_], accC[m_][n_]); \
      accH[m_][n_] = MFMA_(AH[m_], whB[n_], accH[m_][n_]); } } \
    __builtin_amdgcn_s_setprio(0); }

  // One K-step. AIC/AHC hold A(t); AIN/AHN receive A(t+1).
  #define STEP(ACb, WC_, WN_, WS_, AIC, AHC, AIN, AHN) { \
    /* p1: issue wr,wch(t); gate A,wz(t); MFMA z */ \
    wrA[0] = LW(WC_,2,0); wrA[1] = LW(WC_,2,1); \
    wrB[0] = LW(WC_,3,0); wrB[1] = LW(WC_,3,1); \
    wcA[0] = LW(WC_,4,0); wcA[1] = LW(WC_,4,1); \
    whB[0] = LW(WC_,5,0); whB[1] = LW(WC_,5,1); \
    LGKM(8); \
    MZ(AIC, AHC); \
    VM0; BARR; \
    /* p2: stage t+2; issue wz(t+1); gate wr; MFMA r */ \
    STAGE(ACb, WS_); \
    wzA[0] = LW(WN_,0,0); wzA[1] = LW(WN_,0,1); \
    wzB[0] = LW(WN_,1,0); wzB[1] = LW(WN_,1,1); \
    LGKM(8); \
    MR_(AIC, AHC); \
    /* p3: issue A(t+1); gate wch; MFMA c,h */ \
    AIN[0] = LA((ACb)^1,0,0); AIN[1] = LA((ACb)^1,0,1); \
    AIN[2] = LA((ACb)^1,0,2); AIN[3] = LA((ACb)^1,0,3); \
    AHN[0] = LA((ACb)^1,1,0); AHN[1] = LA((ACb)^1,1,1); \
    AHN[2] = LA((ACb)^1,1,2); AHN[3] = LA((ACb)^1,1,3); \
    LGKM(12); \
    MCH(AIC, AHC); \
    if (tt < 29) { oA += 4096u; oW += 12288u; } ++tt; \
  }

  // ---------- prologue ----------
  STAGE(0, 0); oA += 4096u; oW += 12288u;     // t=0 -> Abuf0, Wbuf0
  STAGE(1, 1); oA += 4096u; oW += 12288u;     // t=1 -> Abuf1, Wbuf1 (offsets now t=2)
  VM7;                                        // t0 landed; t1's 7 stay in flight
  BARR;
  aIn0[0] = LA(0,0,0); aIn0[1] = LA(0,0,1); aIn0[2] = LA(0,0,2); aIn0[3] = LA(0,0,3);
  aHx0[0] = LA(0,1,0); aHx0[1] = LA(0,1,1); aHx0[2] = LA(0,1,2); aHx0[3] = LA(0,1,3);
  wzA[0] = LW(0,0,0); wzA[1] = LW(0,0,1);
  wzB[0] = LW(0,1,0); wzB[1] = LW(0,1,1);     // 12 lgkm outstanding

  int tt = 0;
  #pragma unroll 1
  for (int it = 0; it < 5; ++it) {            // t = 0..29
    STEP(0, 0, 1, 2, aIn0, aHx0, aIn1, aHx1)
    STEP(1, 1, 2, 0, aIn1, aHx1, aIn0, aHx0)
    STEP(0, 2, 0, 1, aIn0, aHx0, aIn1, aHx1)
    STEP(1, 0, 1, 2, aIn1, aHx1, aIn0, aHx0)
    STEP(0, 1, 2, 0, aIn0, aHx0, aIn1, aHx1)
    STEP(1, 2, 0, 1, aIn1, aHx1, aIn0, aHx0)
  }
  STEP(0, 0, 1, 2, aIn0, aHx0, aIn1, aHx1)    // t=30
  STEP(1, 1, 2, 0, aIn1, aHx1, aIn0, aHx0)    // t=31
  asm volatile("s_waitcnt vmcnt(0) lgkmcnt(0)" ::: "memory");
  SB0;

  // ---------- epilogue ----------
  const int n0 = j * 64 + wn * 32;
  const int m0 = i * 256 + wm * 64;
  #pragma unroll
  for (int nr = 0; nr < 2; ++nr) {
    int n = n0 + nr * 16 + r15;
    float bz  = bih[n] + bhh[n];
    float br  = bih[1024 + n] + bhh[1024 + n];
    float bcv = bc[n], bhcv = bhc[n];
    #pragma unroll
    for (int mr = 0; mr < 4; ++mr) {
      #pragma unroll
      for (int v = 0; v < 4; ++v) {
        int m = m0 + mr * 16 + q * 4 + v;
        float z  = sigmf(accZ[mr][nr][v] + bz);
        float rr = sigmf(accR[mr][nr][v] + br);
        float cd = tanhf(accC[mr][nr][v] + bcv + rr * (accH[mr][nr][v] + bhcv));
        float h  = Hx[(size_t)m * 1024 + n];
        out[(size_t)m * 1024 + n] = (1.0f - z) * h + z * cd;
      }
    }
  }
  #undef STEP
  #undef MCH
  #undef MR_
  #undef MZ
  #undef MFMA_
  #undef STAGE
  #undef LW
  #undef LA
}

// ---------------- last-resort fp32 fallback ----------------
__global__ __launch_bounds__(256) void gru_fallback(
    const float* __restrict__ In, const float* __restrict__ Hx,
    const float* __restrict__ Wih, const float* __restrict__ bih,
    const float* __restrict__ Whh, const float* __restrict__ bhh,
    const float* __restrict__ Wc, const float* __restrict__ bc,
    const float* __restrict__ Whc, const float* __restrict__ bhc,
    float* __restrict__ out)
{
  __shared__ float sIn[64][17], sHx[64][17];
  __shared__ float sW[6][16][68];
  const int tid = threadIdx.x;
  const int j = blockIdx.x & 15, i = blockIdx.x >> 4;
  const int tx = tid & 15, ty = tid >> 4;
  float accZ[4][4] = {}, accR[4][4] = {}, accC[4][4] = {}, accH[4][4] = {};
  const int ms = tid >> 2, kq = (tid & 3) * 4;
  const int wk = tid >> 4, wn4 = (tid & 15) * 4;
  for (int k0 = 0; k0 < 1024; k0 += 16) {
    __syncthreads();
    {
      float4 a = *(const float4*)&In[(size_t)(i * 64 + ms) * 1024 + k0 + kq];
      sIn[ms][kq] = a.x; sIn[ms][kq + 1] = a.y; sIn[ms][kq + 2] = a.z; sIn[ms][kq + 3] = a.w;
      float4 b = *(const float4*)&Hx[(size_t)(i * 64 + ms) * 1024 + k0 + kq];
      sHx[ms][kq] = b.x; sHx[ms][kq + 1] = b.y; sHx[ms][kq + 2] = b.z; sHx[ms][kq + 3] = b.w;
    }
    {
      float4 w0 = *(const float4*)&Wih[(size_t)(k0 + wk) * 2048 + j * 64 + wn4];
      float4 w1 = *(const float4*)&Wih[(size_t)(k0 + wk) * 2048 + 1024 + j * 64 + wn4];
      float4 w2 = *(const float4*)&Whh[(size_t)(k0 + wk) * 2048 + j * 64 + wn4];
      float4 w3 = *(const float4*)&Whh[(size_t)(k0 + wk) * 2048 + 1024 + j * 64 + wn4];
      float4 w4 = *(const float4*)&Wc[(size_t)(k0 + wk) * 1024 + j * 64 + wn4];
      float4 w5 = *(const float4*)&Whc[(size_t)(k0 + wk) * 1024 + j * 64 + wn4];
      sW[0][wk][wn4] = w0.x; sW[0][wk][wn4+1] = w0.y; sW[0][wk][wn4+2] = w0.z; sW[0][wk][wn4+3] = w0.w;
      sW[1][wk][wn4] = w1.x; sW[1][wk][wn4+1] = w1.y; sW[1][wk][wn4+2] = w1.z; sW[1][wk][wn4+3] = w1.w;
      sW[2][wk][wn4] = w2.x; sW[2][wk][wn4+1] = w2.y; sW[2][wk][wn4+2] = w2.z; sW[2][wk][wn4+3] = w2.w;
      sW[3][wk][wn4] = w3.x; sW[3][wk][wn4+1] = w3.y; sW[3][wk][wn4+2] = w3.z; sW[3][wk][wn4+3] = w3.w;
      sW[4][wk][wn4] = w4.x; sW[4][wk][wn4+1] = w4.y; sW[4][wk][wn4+2] = w4.z; sW[4][wk][wn4+3] = w4.w;
      sW[5][wk][wn4] = w5.x; sW[5][wk][wn4+1] = w5.y; sW[5][wk][wn4+2] = w5.z; sW[5][wk][wn4+3] = w5.w;
    }
    __syncthreads();
    for (int kk = 0; kk < 16; ++kk) {
      float aI[4], aH[4];
      #pragma unroll
      for (int im = 0; im < 4; ++im) { aI[im] = sIn[ty * 4 + im][kk]; aH[im] = sHx[ty * 4 + im][kk]; }
      #pragma unroll
      for (int jn = 0; jn < 4; ++jn) {
        float w0 = sW[0][kk][tx * 4 + jn], w1 = sW[1][kk][tx * 4 + jn], w2 = sW[2][kk][tx * 4 + jn];
        float w3 = sW[3][kk][tx * 4 + jn], w4 = sW[4][kk][tx * 4 + jn], w5 = sW[5][kk][tx * 4 + jn];
        #pragma unroll
        for (int im = 0; im < 4; ++im) {
          accZ[im][jn] += aI[im] * w0 + aH[im] * w2;
          accR[im][jn] += aI[im] * w1 + aH[im] * w3;
          accC[im][jn] += aI[im] * w4;
          accH[im][jn] += aH[im] * w5;
        }
      }
    }
  }
  #pragma unroll
  for (int jn = 0; jn < 4; ++jn) {
    int n = j * 64 + tx * 4 + jn;
    float bz  = bih[n] + bhh[n];
    float br  = bih[1024 + n] + bhh[1024 + n];
    float bcv = bc[n], bhcv = bhc[n];
    #pragma unroll
    for (int im = 0; im < 4; ++im) {
      int m = i * 64 + ty * 4 + im;
      float z  = sigmf(accZ[im][jn] + bz);
      float rr = sigmf(accR[im][jn] + br);
      float cd = tanhf(accC[im][jn] + bcv + rr * (accH[im][jn] + bhcv));
      float h  = Hx[(size_t)m * 1024 + n];
      out[(size_t)m * 1024 + n] = (1.0f - z) * h + z * cd;
    }
  }
}

extern "C" void kernel_launch(void* const* d_in, const int* in_sizes, int n_in,
                              void* d_out, int out_size, void* d_ws, size_t ws_size,
                              hipStream_t stream) {
  const float* In  = (const float*)d_in[0];
  const float* Hx  = (const float*)d_in[1];
  const float* Wih = (const float*)d_in[2];
  const float* bih = (const float*)d_in[3];
  const float* Whh = (const float*)d_in[4];
  const float* bhh = (const float*)d_in[5];
  const float* Wc  = (const float*)d_in[6];
  const float* bc  = (const float*)d_in[7];
  const float* Whc = (const float*)d_in[8];
  const float* bhc = (const float*)d_in[9];
  float* out = (float*)d_out;

  const size_t WS_NEED = 46137344ull;
  if (ws_size >= WS_NEED) {
    unsigned short* ws = (unsigned short*)d_ws;
    cvt_all<<<11264, 256, 0, stream>>>(In, Hx, Wih, Whh, Wc, Whc, ws);
    gru_gemm<<<512, 512, 0, stream>>>(ws, Hx, bih, bhh, bc, bhc, out);
  } else {
    gru_fallback<<<2048, 256, 0, stream>>>(In, Hx, Wih, bih, Whh, bhh, Wc, bc, Whc, bhc, out);
  }
}

// Round 7
// 139.322 us; speedup vs baseline: 1.4717x; 1.4717x over previous
//
#include <hip/hip_runtime.h>
#include <hip/hip_bf16.h>
#include <cmath>

// GRU cell fused, round 7: round-1 proven shell (BM=128 x BN=64, 4 waves,
// BK=32, verified swizzle/layout/epilogue) + clean T3-minimum pipeline:
//   prologue: STAGE(buf0, 0); barrier;
//   loop:     STAGE(other, t+1); compute(cur); __syncthreads();
// ONE barrier per step, stage issued BEFORE compute (DMA latency hides under
// ds_read+MFMA), NO sched_barrier / setprio / inline waitcnt anywhere.
// + XCD swizzle (1024 % 8 == 0, bijective).
// ws layout (ushort elems) — identical to round 1:
//   wsIn  @ 0        : [64 mtile][32 kstep][128x32 swz]
//   wsHx  @ 8388608
//   wsWih @ 16777216 : [32 ntile][32 kstep][64x32 swz]
//   wsWhh @ 18874368
//   wsWc  @ 20971520
//   wsWhc @ 22020096

typedef __attribute__((ext_vector_type(8))) short bf16x8;
typedef __attribute__((ext_vector_type(4))) float f32x4;
typedef unsigned int u32;

typedef const __attribute__((address_space(1))) u32 gu32;
typedef __attribute__((address_space(3))) u32 su32;

__device__ __forceinline__ unsigned short f2bf(float f) {
  union { float f; u32 u; } v; v.f = f;
  u32 u = v.u;
  u += 0x7FFFu + ((u >> 16) & 1u);   // RTNE
  return (unsigned short)(u >> 16);
}
__device__ __forceinline__ void gload16(void* ldsp, const void* gp) {
  __builtin_amdgcn_global_load_lds((gu32*)gp, (su32*)ldsp, 16, 0, 0);
}
__device__ __forceinline__ float sigmf(float x) { return 1.0f / (1.0f + __expf(-x)); }

// ---------------- merged prepass: fp32 -> bf16 swizzled tiles (proven) ----------------
__global__ __launch_bounds__(256) void cvt_all(
    const float* __restrict__ In, const float* __restrict__ Hx,
    const float* __restrict__ Wih, const float* __restrict__ Whh,
    const float* __restrict__ Wc,  const float* __restrict__ Whc,
    unsigned short* __restrict__ wsIn, unsigned short* __restrict__ wsHx,
    unsigned short* __restrict__ wsWih, unsigned short* __restrict__ wsWhh,
    unsigned short* __restrict__ wsWc,  unsigned short* __restrict__ wsWhc)
{
  int bid = blockIdx.x;
  if (bid < 8192) {
    int gid = bid * 256 + threadIdx.x;
    const float* src; unsigned short* dst; int idx;
    if (gid < (1 << 20)) { src = In; dst = wsIn; idx = gid; }
    else                 { src = Hx; dst = wsHx; idx = gid - (1 << 20); }
    int m = idx >> 7, t = idx & 127;
    const float4* s = (const float4*)(src + (size_t)m * 1024 + t * 8);
    float4 a = s[0], b = s[1];
    int row = m & 127;
    size_t tile = (size_t)(m >> 7) * 32 + (t >> 2);
    int sw = (t & 3) ^ ((row >> 1) & 3);
    bf16x8 v;
    v[0] = (short)f2bf(a.x); v[1] = (short)f2bf(a.y); v[2] = (short)f2bf(a.z); v[3] = (short)f2bf(a.w);
    v[4] = (short)f2bf(b.x); v[5] = (short)f2bf(b.y); v[6] = (short)f2bf(b.z); v[7] = (short)f2bf(b.w);
    *(bf16x8*)(dst + tile * 4096 + row * 32 + sw * 8) = v;
  } else {
    int wb = bid - 8192;
    const float* W; unsigned short* dst; int NW; int local;
    if (wb < 1024)      { W = Wih; dst = wsWih; NW = 2048; local = wb; }
    else if (wb < 2048) { W = Whh; dst = wsWhh; NW = 2048; local = wb - 1024; }
    else if (wb < 2560) { W = Wc;  dst = wsWc;  NW = 1024; local = wb - 2048; }
    else                { W = Whc; dst = wsWhc; NW = 1024; local = wb - 2560; }
    int nb = local >> 5, kb = local & 31;
    int n  = nb * 64 + (threadIdx.x & 63);
    int k0 = kb * 32 + (threadIdx.x >> 6) * 8;
    bf16x8 v;
    #pragma unroll
    for (int b = 0; b < 8; ++b) v[b] = (short)f2bf(W[(size_t)(k0 + b) * NW + n]);
    int row = n & 63;
    size_t tile = (size_t)(n >> 6) * 32 + (k0 >> 5);
    int sw = ((k0 >> 3) & 3) ^ ((row >> 1) & 3);
    *(bf16x8*)(dst + tile * 2048 + row * 32 + sw * 8) = v;
  }
}

// ---------------- fused GEMM + GRU epilogue ----------------
// block: 256 thr = 4 waves (2x2), tile BM=128 x BN=64, BK=32, double-buffered.
// LDS buffer (ushort, per buf 20480): sIn[0,4096) sHx[4096,8192) W t=0..5 at 8192+t*2048
__global__ __launch_bounds__(256, 2) void gru_gemm(
    const unsigned short* __restrict__ wsIn, const unsigned short* __restrict__ wsHx,
    const unsigned short* __restrict__ wsWih, const unsigned short* __restrict__ wsWhh,
    const unsigned short* __restrict__ wsWc, const unsigned short* __restrict__ wsWhc,
    const float* __restrict__ Hx,
    const float* __restrict__ bih, const float* __restrict__ bhh,
    const float* __restrict__ bc, const float* __restrict__ bhc,
    float* __restrict__ out)
{
  __shared__ unsigned short lds[40960];   // 80 KB = 2 x 40 KB
  const int tid  = threadIdx.x;
  const int lane = tid & 63;
  const int wave = tid >> 6;
  const int wm = wave >> 1, wn = wave & 1;
  const int bid = blockIdx.x;
  const int swz = (bid & 7) * 128 + (bid >> 3);   // bijective XCD swizzle (1024%8==0)
  const int j = swz & 15;     // n-block (64 cols)
  const int i = swz >> 4;     // m-block (128 rows)

  // per-wave staging plan: 10 chunks of 1KB each (64 lanes x 16B)
  const unsigned short* srcB[10];
  int strd[10];
  #pragma unroll
  for (int c0 = 0; c0 < 10; ++c0) {
    int c = wave * 10 + c0;
    const unsigned short* p; int st;
    if (c < 8)       { p = wsIn + (size_t)i * 131072 + c * 512;        st = 4096; }
    else if (c < 16) { p = wsHx + (size_t)i * 131072 + (c - 8) * 512;  st = 4096; }
    else {
      int t = (c - 16) >> 2, cc = (c - 16) & 3;
      const unsigned short* base; int nb;
      if (t == 0)      { base = wsWih; nb = j; }
      else if (t == 1) { base = wsWih; nb = j + 16; }
      else if (t == 2) { base = wsWhh; nb = j; }
      else if (t == 3) { base = wsWhh; nb = j + 16; }
      else if (t == 4) { base = wsWc;  nb = j; }
      else             { base = wsWhc; nb = j; }
      p = base + (size_t)nb * 65536 + cc * 512;
      st = 2048;
    }
    srcB[c0] = p + lane * 8;
    strd[c0] = st;
  }
  const int stageOff = (wave * 10) * 512;   // within a buffer

  f32x4 accZ[4][2], accR[4][2], accC[4][2], accH[4][2];
  #pragma unroll
  for (int a = 0; a < 4; ++a)
    #pragma unroll
    for (int b = 0; b < 2; ++b) {
      accZ[a][b] = (f32x4)(0.0f); accR[a][b] = (f32x4)(0.0f);
      accC[a][b] = (f32x4)(0.0f); accH[a][b] = (f32x4)(0.0f);
    }

  const int r15 = lane & 15;
  const int q   = lane >> 4;

  int aOff[4], wOff[2];
  #pragma unroll
  for (int mr = 0; mr < 4; ++mr) {
    int row = wm * 64 + mr * 16 + r15;
    aOff[mr] = row * 32 + ((q ^ ((row >> 1) & 3)) << 3);
  }
  #pragma unroll
  for (int nr = 0; nr < 2; ++nr) {
    int row = wn * 32 + nr * 16 + r15;
    wOff[nr] = row * 32 + ((q ^ ((row >> 1) & 3)) << 3);
  }

  auto stage = [&](int bufBase, int s) {
    #pragma unroll
    for (int c0 = 0; c0 < 10; ++c0)
      gload16((void*)&lds[bufBase + stageOff + c0 * 512],
              (const void*)(srcB[c0] + (size_t)s * strd[c0]));
  };

  auto compute = [&](const unsigned short* __restrict__ L) {
    bf16x8 aIn[4], aHx[4];
    #pragma unroll
    for (int mr = 0; mr < 4; ++mr) {
      aIn[mr] = *(const bf16x8*)&L[aOff[mr]];
      aHx[mr] = *(const bf16x8*)&L[4096 + aOff[mr]];
    }
    bf16x8 wf[6][2];
    #pragma unroll
    for (int t = 0; t < 6; ++t)
      #pragma unroll
      for (int nr = 0; nr < 2; ++nr)
        wf[t][nr] = *(const bf16x8*)&L[8192 + t * 2048 + wOff[nr]];

    #pragma unroll
    for (int mr = 0; mr < 4; ++mr)
      #pragma unroll
      for (int nr = 0; nr < 2; ++nr) {
        accZ[mr][nr] = __builtin_amdgcn_mfma_f32_16x16x32_bf16(aIn[mr], wf[0][nr], accZ[mr][nr], 0, 0, 0);
        accZ[mr][nr] = __builtin_amdgcn_mfma_f32_16x16x32_bf16(aHx[mr], wf[2][nr], accZ[mr][nr], 0, 0, 0);
        accR[mr][nr] = __builtin_amdgcn_mfma_f32_16x16x32_bf16(aIn[mr], wf[1][nr], accR[mr][nr], 0, 0, 0);
        accR[mr][nr] = __builtin_amdgcn_mfma_f32_16x16x32_bf16(aHx[mr], wf[3][nr], accR[mr][nr], 0, 0, 0);
        accC[mr][nr] = __builtin_amdgcn_mfma_f32_16x16x32_bf16(aIn[mr], wf[4][nr], accC[mr][nr], 0, 0, 0);
        accH[mr][nr] = __builtin_amdgcn_mfma_f32_16x16x32_bf16(aHx[mr], wf[5][nr], accH[mr][nr], 0, 0, 0);
      }
  };

  // prologue: stage step 0 into buf0, drain once
  stage(0, 0);
  __syncthreads();

  // main loop: one barrier per step; stage(next) issued BEFORE compute(cur)
  #pragma unroll 1
  for (int it = 0; it < 16; ++it) {
    const int s = it * 2;
    stage(20480, s + 1);                 // next tile -> buf1 (in flight under compute)
    compute(&lds[0]);                    // step s from buf0
    __syncthreads();                     // buf1 ready; all reads of buf0 done
    if (it < 15) stage(0, s + 2);        // next tile -> buf0
    compute(&lds[20480]);                // step s+1 from buf1
    __syncthreads();
  }

  // epilogue: D layout col = lane&15 (n), row = q*4+v (m)
  const int n0 = j * 64 + wn * 32;
  const int m0 = i * 128 + wm * 64;
  #pragma unroll
  for (int nr = 0; nr < 2; ++nr) {
    int n = n0 + nr * 16 + r15;
    float bz  = bih[n] + bhh[n];
    float br  = bih[1024 + n] + bhh[1024 + n];
    float bcv = bc[n], bhcv = bhc[n];
    #pragma unroll
    for (int mr = 0; mr < 4; ++mr) {
      #pragma unroll
      for (int v = 0; v < 4; ++v) {
        int m = m0 + mr * 16 + q * 4 + v;
        float z  = sigmf(accZ[mr][nr][v] + bz);
        float rr = sigmf(accR[mr][nr][v] + br);
        float cd = tanhf(accC[mr][nr][v] + bcv + rr * (accH[mr][nr][v] + bhcv));
        float h  = Hx[(size_t)m * 1024 + n];
        out[(size_t)m * 1024 + n] = (1.0f - z) * h + z * cd;
      }
    }
  }
}

// ---------------- last-resort fp32 fallback ----------------
__global__ __launch_bounds__(256) void gru_fallback(
    const float* __restrict__ In, const float* __restrict__ Hx,
    const float* __restrict__ Wih, const float* __restrict__ bih,
    const float* __restrict__ Whh, const float* __restrict__ bhh,
    const float* __restrict__ Wc, const float* __restrict__ bc,
    const float* __restrict__ Whc, const float* __restrict__ bhc,
    float* __restrict__ out)
{
  __shared__ float sIn[64][17], sHx[64][17];
  __shared__ float sW[6][16][68];
  const int tid = threadIdx.x;
  const int j = blockIdx.x & 15, i = blockIdx.x >> 4;
  const int tx = tid & 15, ty = tid >> 4;
  float accZ[4][4] = {}, accR[4][4] = {}, accC[4][4] = {}, accH[4][4] = {};
  const int ms = tid >> 2, kq = (tid & 3) * 4;
  const int wk = tid >> 4, wn4 = (tid & 15) * 4;
  for (int k0 = 0; k0 < 1024; k0 += 16) {
    __syncthreads();
    {
      float4 a = *(const float4*)&In[(size_t)(i * 64 + ms) * 1024 + k0 + kq];
      sIn[ms][kq] = a.x; sIn[ms][kq + 1] = a.y; sIn[ms][kq + 2] = a.z; sIn[ms][kq + 3] = a.w;
      float4 b = *(const float4*)&Hx[(size_t)(i * 64 + ms) * 1024 + k0 + kq];
      sHx[ms][kq] = b.x; sHx[ms][kq + 1] = b.y; sHx[ms][kq + 2] = b.z; sHx[ms][kq + 3] = b.w;
    }
    {
      float4 w0 = *(const float4*)&Wih[(size_t)(k0 + wk) * 2048 + j * 64 + wn4];
      float4 w1 = *(const float4*)&Wih[(size_t)(k0 + wk) * 2048 + 1024 + j * 64 + wn4];
      float4 w2 = *(const float4*)&Whh[(size_t)(k0 + wk) * 2048 + j * 64 + wn4];
      float4 w3 = *(const float4*)&Whh[(size_t)(k0 + wk) * 2048 + 1024 + j * 64 + wn4];
      float4 w4 = *(const float4*)&Wc[(size_t)(k0 + wk) * 1024 + j * 64 + wn4];
      float4 w5 = *(const float4*)&Whc[(size_t)(k0 + wk) * 1024 + j * 64 + wn4];
      sW[0][wk][wn4] = w0.x; sW[0][wk][wn4+1] = w0.y; sW[0][wk][wn4+2] = w0.z; sW[0][wk][wn4+3] = w0.w;
      sW[1][wk][wn4] = w1.x; sW[1][wk][wn4+1] = w1.y; sW[1][wk][wn4+2] = w1.z; sW[1][wk][wn4+3] = w1.w;
      sW[2][wk][wn4] = w2.x; sW[2][wk][wn4+1] = w2.y; sW[2][wk][wn4+2] = w2.z; sW[2][wk][wn4+3] = w2.w;
      sW[3][wk][wn4] = w3.x; sW[3][wk][wn4+1] = w3.y; sW[3][wk][wn4+2] = w3.z; sW[3][wk][wn4+3] = w3.w;
      sW[4][wk][wn4] = w4.x; sW[4][wk][wn4+1] = w4.y; sW[4][wk][wn4+2] = w4.z; sW[4][wk][wn4+3] = w4.w;
      sW[5][wk][wn4] = w5.x; sW[5][wk][wn4+1] = w5.y; sW[5][wk][wn4+2] = w5.z; sW[5][wk][wn4+3] = w5.w;
    }
    __syncthreads();
    for (int kk = 0; kk < 16; ++kk) {
      float aI[4], aH[4];
      #pragma unroll
      for (int im = 0; im < 4; ++im) { aI[im] = sIn[ty * 4 + im][kk]; aH[im] = sHx[ty * 4 + im][kk]; }
      #pragma unroll
      for (int jn = 0; jn < 4; ++jn) {
        float w0 = sW[0][kk][tx * 4 + jn], w1 = sW[1][kk][tx * 4 + jn], w2 = sW[2][kk][tx * 4 + jn];
        float w3 = sW[3][kk][tx * 4 + jn], w4 = sW[4][kk][tx * 4 + jn], w5 = sW[5][kk][tx * 4 + jn];
        #pragma unroll
        for (int im = 0; im < 4; ++im) {
          accZ[im][jn] += aI[im] * w0 + aH[im] * w2;
          accR[im][jn] += aI[im] * w1 + aH[im] * w3;
          accC[im][jn] += aI[im] * w4;
          accH[im][jn] += aH[im] * w5;
        }
      }
    }
  }
  #pragma unroll
  for (int jn = 0; jn < 4; ++jn) {
    int n = j * 64 + tx * 4 + jn;
    float bz  = bih[n] + bhh[n];
    float br  = bih[1024 + n] + bhh[1024 + n];
    float bcv = bc[n], bhcv = bhc[n];
    #pragma unroll
    for (int im = 0; im < 4; ++im) {
      int m = i * 64 + ty * 4 + im;
      float z  = sigmf(accZ[im][jn] + bz);
      float rr = sigmf(accR[im][jn] + br);
      float cd = tanhf(accC[im][jn] + bcv + rr * (accH[im][jn] + bhcv));
      float h  = Hx[(size_t)m * 1024 + n];
      out[(size_t)m * 1024 + n] = (1.0f - z) * h + z * cd;
    }
  }
}

extern "C" void kernel_launch(void* const* d_in, const int* in_sizes, int n_in,
                              void* d_out, int out_size, void* d_ws, size_t ws_size,
                              hipStream_t stream) {
  const float* In  = (const float*)d_in[0];
  const float* Hx  = (const float*)d_in[1];
  const float* Wih = (const float*)d_in[2];
  const float* bih = (const float*)d_in[3];
  const float* Whh = (const float*)d_in[4];
  const float* bhh = (const float*)d_in[5];
  const float* Wc  = (const float*)d_in[6];
  const float* bc  = (const float*)d_in[7];
  const float* Whc = (const float*)d_in[8];
  const float* bhc = (const float*)d_in[9];
  float* out = (float*)d_out;

  const size_t WS_NEED = 46137344ull;
  if (ws_size >= WS_NEED) {
    unsigned short* ws    = (unsigned short*)d_ws;
    unsigned short* wsIn  = ws;
    unsigned short* wsHx  = ws + 8388608;
    unsigned short* wsWih = ws + 16777216;
    unsigned short* wsWhh = ws + 18874368;
    unsigned short* wsWc  = ws + 20971520;
    unsigned short* wsWhc = ws + 22020096;
    cvt_all<<<11264, 256, 0, stream>>>(In, Hx, Wih, Whh, Wc, Whc,
                                       wsIn, wsHx, wsWih, wsWhh, wsWc, wsWhc);
    gru_gemm<<<1024, 256, 0, stream>>>(wsIn, wsHx, wsWih, wsWhh, wsWc, wsWhc,
                                       Hx, bih, bhh, bc, bhc, out);
  } else {
    gru_fallback<<<2048, 256, 0, stream>>>(In, Hx, Wih, bih, Whh, bhh, Wc, bc, Whc, bhc, out);
  }
}